// Round 8
// baseline (378.047 us; speedup 1.0000x reference)
//
#include <hip/hip_runtime.h>

// MultiHeadAttention: B=2, N=2048, C=768, H=12, DH=64. fp32 in/out, bf16 MFMA compute.
// R8: (1) GEMM LDS XOR-swizzle: source-permuted global_load_lds + XOR'd consumer
// oct index -> conflict-free ds_read_b128 with no pad (R7 had 16-way conflicts).
// (2) attn barrier-free: 512-thr blocks, 8 waves = 2(q-half) x 4(key-quarter);
// each wave reads its private K/V fragment slices DIRECTLY from global (L2);
// LDS only for the final 2-round cross-wave O reduction.  No __syncthreads in
// the K-loop.

typedef __bf16 bf16_t;
typedef __bf16 bf16x8 __attribute__((ext_vector_type(8)));
typedef __bf16 bf16x4 __attribute__((ext_vector_type(4)));
typedef float  floatx4 __attribute__((ext_vector_type(4)));
typedef unsigned int u32;

#define MFMA32(a, b, c) __builtin_amdgcn_mfma_f32_16x16x32_bf16(a, b, c, 0, 0, 0)

__device__ __forceinline__ void async16(const bf16_t* g, bf16_t* l) {
  __builtin_amdgcn_global_load_lds(
      (const __attribute__((address_space(1))) u32*)g,
      (__attribute__((address_space(3))) u32*)l, 16, 0, 0);
}

// ---------------------------------------------------------------- converts --
__global__ __launch_bounds__(256) void cvt_x_kernel(const float* __restrict__ x,
                                                    bf16_t* __restrict__ xb) {
  int i = blockIdx.x * 256 + threadIdx.x;
  floatx4 v = ((const floatx4*)x)[i];
  bf16x4 o;
  o[0] = (bf16_t)v[0]; o[1] = (bf16_t)v[1]; o[2] = (bf16_t)v[2]; o[3] = (bf16_t)v[3];
  ((bf16x4*)xb)[i] = o;
}

// W [in=768][out=768] fp32 -> WT [out][in] bf16; blockIdx.z picks which matrix.
__global__ __launch_bounds__(256) void cvt_wt_kernel(
    const float* __restrict__ W0, const float* __restrict__ W1,
    const float* __restrict__ W2, const float* __restrict__ W3,
    bf16_t* __restrict__ T0, bf16_t* __restrict__ T1,
    bf16_t* __restrict__ T2, bf16_t* __restrict__ T3) {
  const int z = blockIdx.z;
  const float* W = (z == 0) ? W0 : (z == 1) ? W1 : (z == 2) ? W2 : W3;
  bf16_t* WT = (z == 0) ? T0 : (z == 1) ? T1 : (z == 2) ? T2 : T3;
  __shared__ bf16_t T[64][65];
  const int c = threadIdx.x & 63, r0 = threadIdx.x >> 6;
#pragma unroll
  for (int p = 0; p < 16; ++p) {
    int r = p * 4 + r0;
    T[r][c] = (bf16_t)W[(blockIdx.y * 64 + r) * 768 + blockIdx.x * 64 + c];
  }
  __syncthreads();
#pragma unroll
  for (int p = 0; p < 16; ++p) {
    int r = p * 4 + r0;
    WT[(blockIdx.x * 64 + r) * 768 + blockIdx.y * 64 + c] = T[c][r];
  }
}

// ------------------------------------------------------------------- GEMMs --
// 128x128 tile, BK=64, pitch 64 elems (128 B), XOR swizzle: oct j of row r is
// stored at slot j^(r&7).  Staging permutes the SOURCE column (LDS dst must be
// lane-linear for global_load_lds); consumers XOR their oct index.  All
// fragment reads then spread over all 32 banks (2 lanes/bank = free).

// Fragment-order layouts (per bh, per 128-key tile kt):
//  K: elem(key,d) -> kt*8192 + ((nk*2+kk)*64 + quad*16 + l15)*8 + j
//     nk=key128>>4, l15=key128&15, kk=d>>5, quad=(d>>3)&3, j=d&7
//  V (sigma-permuted for x32 PV): elem(key,d) ->
//     kt*8192 + ((g*4+nd)*64 + qv*16 + dl15)*8 + jv
//     g=key128>>5, o=key128&31, qv=(o&15)>>2, jv=(o&3)+((o&16)>>2),
//     nd=d>>4, dl15=d&15

// Fused QKV, M = output channels (768), N = tokens (4096).
__global__ __launch_bounds__(256) void gemm_qkv(
    const bf16_t* __restrict__ Xb, const bf16_t* __restrict__ WqT,
    const bf16_t* __restrict__ WkT, const bf16_t* __restrict__ WvT,
    const float* __restrict__ bq, const float* __restrict__ bk,
    const float* __restrict__ bv, bf16_t* __restrict__ qw,
    bf16_t* __restrict__ kw, bf16_t* __restrict__ vtw) {
  __shared__ bf16_t Al[128 * 64];
  __shared__ bf16_t Bl[128 * 64];
  const int z = blockIdx.z;
  const bf16_t* Wt = (z == 0) ? WqT : (z == 1) ? WkT : WvT;
  const float* bias = (z == 0) ? bq : (z == 1) ? bk : bv;
  const float oscale = (z == 0) ? 0.18033688011112042f : 1.0f;  // 0.125*log2(e)

  const int tid = threadIdx.x, lane = tid & 63, w = tid >> 6;
  const int wr = w >> 1, wc = w & 1;
  const int l15 = lane & 15, quad = lane >> 4;
  const int xr = l15 & 7;
  const int m0 = blockIdx.y * 128, n0 = blockIdx.x * 128;

  floatx4 acc[4][4] = {};

  for (int kt = 0; kt < 768; kt += 64) {
#pragma unroll
    for (int p = 0; p < 4; ++p) {               // 16 chunks of 512 elems total
      const int cb = (p * 4 + w) * 64;          // wave-uniform chunk base
      const int c = cb + lane;
      const int r = c >> 3, j = (c & 7) ^ (r & 7);   // source col permuted
      async16(&Wt[(m0 + r) * 768 + kt + j * 8], &Al[cb * 8]);
      async16(&Xb[(n0 + r) * 768 + kt + j * 8], &Bl[cb * 8]);
    }
    __syncthreads();
#pragma unroll
    for (int kk = 0; kk < 2; ++kk) {
      bf16x8 af[4], bfr[4];
#pragma unroll
      for (int i = 0; i < 4; ++i) {
        const int sl = ((kk * 4 + quad) ^ xr) * 8;   // swizzled oct slot
        af[i]  = *(bf16x8*)&Al[(wr * 64 + i * 16 + l15) * 64 + sl];
        bfr[i] = *(bf16x8*)&Bl[(wc * 64 + i * 16 + l15) * 64 + sl];
      }
#pragma unroll
      for (int mi = 0; mi < 4; ++mi)
#pragma unroll
        for (int ni = 0; ni < 4; ++ni)
          acc[mi][ni] = MFMA32(af[mi], bfr[ni], acc[mi][ni]);
    }
    __syncthreads();
  }

  const int hh = (m0 + wr * 64) >> 6;  // head (64-aligned per wave-row)
#pragma unroll
  for (int mi = 0; mi < 4; ++mi) {
    const int d0 = mi * 16 + quad * 4;           // d within head, multiple of 4
    const int gm0 = m0 + wr * 64 + d0;
    float bv4[4];
#pragma unroll
    for (int r = 0; r < 4; ++r) bv4[r] = bias[gm0 + r];
#pragma unroll
    for (int ni = 0; ni < 4; ++ni) {
      const int gn = n0 + wc * 64 + ni * 16 + l15;
      const int bb = gn >> 11, tok = gn & 2047;
      const int bh = bb * 12 + hh;
      if (z == 0) {
        bf16x4 pk;
#pragma unroll
        for (int r = 0; r < 4; ++r)
          pk[r] = (bf16_t)((acc[mi][ni][r] + bv4[r]) * oscale);
        *(bf16x4*)&qw[bh * 131072 + tok * 64 + d0] = pk;
      } else if (z == 1) {
        const int kt2 = tok >> 7, k128 = tok & 127;
        const int nk = k128 >> 4, kl15 = k128 & 15;
        const int kk = d0 >> 5, kq = (d0 >> 3) & 3, j0 = d0 & 7;
        bf16x4 pk;
#pragma unroll
        for (int r = 0; r < 4; ++r)
          pk[r] = (bf16_t)(acc[mi][ni][r] + bv4[r]);
        *(bf16x4*)&kw[bh * 131072 + kt2 * 8192 +
                      ((nk * 2 + kk) * 64 + kq * 16 + kl15) * 8 + j0] = pk;
      } else {
        const int kt2 = tok >> 7, k128 = tok & 127;
        const int g = k128 >> 5, o = k128 & 31;
        const int qv = (o & 15) >> 2, jv = (o & 3) + ((o & 16) >> 2);
        // d = d0 + r -> nd = mi, dl15 = quad*4 + r
        const int base = bh * 131072 + kt2 * 8192 +
                         ((g * 4 + mi) * 64 + qv * 16 + quad * 4) * 8 + jv;
#pragma unroll
        for (int r = 0; r < 4; ++r)
          vtw[base + r * 8] = (bf16_t)(acc[mi][ni][r] + bv4[r]);
      }
    }
  }
}

// Output projection, M = channels: out fp32 [4096 tok][768 ch] via float4 stores.
__global__ __launch_bounds__(256) void gemm_proj(
    const bf16_t* __restrict__ Yb, const bf16_t* __restrict__ WpT,
    const float* __restrict__ bias, float* __restrict__ out) {
  __shared__ bf16_t Al[128 * 64];
  __shared__ bf16_t Bl[128 * 64];
  const int tid = threadIdx.x, lane = tid & 63, w = tid >> 6;
  const int wr = w >> 1, wc = w & 1;
  const int l15 = lane & 15, quad = lane >> 4;
  const int xr = l15 & 7;
  const int m0 = blockIdx.y * 128, n0 = blockIdx.x * 128;

  floatx4 acc[4][4] = {};

  for (int kt = 0; kt < 768; kt += 64) {
#pragma unroll
    for (int p = 0; p < 4; ++p) {
      const int cb = (p * 4 + w) * 64;
      const int c = cb + lane;
      const int r = c >> 3, j = (c & 7) ^ (r & 7);
      async16(&WpT[(m0 + r) * 768 + kt + j * 8], &Al[cb * 8]);
      async16(&Yb[(n0 + r) * 768 + kt + j * 8], &Bl[cb * 8]);
    }
    __syncthreads();
#pragma unroll
    for (int kk = 0; kk < 2; ++kk) {
      bf16x8 af[4], bfr[4];
#pragma unroll
      for (int i = 0; i < 4; ++i) {
        const int sl = ((kk * 4 + quad) ^ xr) * 8;
        af[i]  = *(bf16x8*)&Al[(wr * 64 + i * 16 + l15) * 64 + sl];
        bfr[i] = *(bf16x8*)&Bl[(wc * 64 + i * 16 + l15) * 64 + sl];
      }
#pragma unroll
      for (int mi = 0; mi < 4; ++mi)
#pragma unroll
        for (int ni = 0; ni < 4; ++ni)
          acc[mi][ni] = MFMA32(af[mi], bfr[ni], acc[mi][ni]);
    }
    __syncthreads();
  }

#pragma unroll
  for (int mi = 0; mi < 4; ++mi) {
    const int gm0 = m0 + wr * 64 + mi * 16 + quad * 4;
    floatx4 bv4;
#pragma unroll
    for (int r = 0; r < 4; ++r) bv4[r] = bias[gm0 + r];
#pragma unroll
    for (int ni = 0; ni < 4; ++ni) {
      const int gn = n0 + wc * 64 + ni * 16 + l15;
      floatx4 v = acc[mi][ni] + bv4;
      *(floatx4*)&out[gn * 768 + gm0] = v;
    }
  }
}

// --------------------------------------------------------------- attention --
// Block: one (b,h), 64 Q rows, 512 threads = 8 waves.  Wave w: wq=w&1 picks the
// 32-q half, wk=w>>1 picks the 32-key quarter of each 128-key tile.  Each wave
// reads its private K/V fragment slices directly from global (lane-contiguous
// b128, L2-resident) -> NO LDS staging, NO barriers in the K-loop.  End: 2-round
// tree reduction of O over the 4 key-quarters via LDS.
__global__ __launch_bounds__(512, 4) void attn_kernel(
    const bf16_t* __restrict__ Q, const bf16_t* __restrict__ Kf,
    const bf16_t* __restrict__ Vf, bf16_t* __restrict__ Y) {
  __shared__ __align__(16) float Ox[8][2][2][64][4];  // 32 KB exchange
  __shared__ float Ls[4][2][2][16];                   // [wk][wq][ni][l15]

  const int tid = threadIdx.x, lane = tid & 63, w = tid >> 6;
  const int wq = w & 1, wk = w >> 1;
  const int l15 = lane & 15, quad = lane >> 4;
  const int bh = blockIdx.y;
  const int q0 = blockIdx.x * 64;
  const bf16_t* Qb = Q + bh * 131072;
  const bf16_t* Kb = Kf + bh * 131072;
  const bf16_t* Vb = Vf + bh * 131072;

  bf16x8 qf[2][2];  // B-frag: n=q over l15, k=dh over quad*8+j
#pragma unroll
  for (int ni = 0; ni < 2; ++ni)
#pragma unroll
    for (int kk = 0; kk < 2; ++kk)
      qf[ni][kk] = *(const bf16x8*)&Qb[(q0 + wq * 32 + ni * 16 + l15) * 64 +
                                       kk * 32 + quad * 8];

  floatx4 oacc[2][4] = {};   // [ni(q16)][nd(d16)], partial over this wave's keys
  float lsum[2] = {0.f, 0.f};

  for (int kt = 0; kt < 16; ++kt) {
    const bf16_t* kg = Kb + kt * 8192;
    const bf16_t* vg = Vb + kt * 8192;

    // K frags for this wave's 32 keys (2 x 16-key groups x 2 k-halves)
    bf16x8 kfr[2][2];
#pragma unroll
    for (int mt = 0; mt < 2; ++mt)
#pragma unroll
      for (int kk = 0; kk < 2; ++kk)
        kfr[mt][kk] = *(const bf16x8*)&kg[((wk * 2 + mt) * 2 + kk) * 512 + lane * 8];

    // S^T = K*Q^T: 32 keys x 32 q
    floatx4 s[2][2] = {};  // [mt][ni]
#pragma unroll
    for (int mt = 0; mt < 2; ++mt)
#pragma unroll
      for (int kk = 0; kk < 2; ++kk)
#pragma unroll
        for (int ni = 0; ni < 2; ++ni)
          s[mt][ni] = MFMA32(kfr[mt][kk], qf[ni][kk], s[mt][ni]);

    // P = exp2(S) packed into x32 A-frags (key perm sigma matches V layout)
    bf16x8 pk[2];
#pragma unroll
    for (int mt = 0; mt < 2; ++mt)
#pragma unroll
      for (int ni = 0; ni < 2; ++ni)
#pragma unroll
        for (int r = 0; r < 4; ++r) {
          const float pv = __builtin_amdgcn_exp2f(s[mt][ni][r]);
          lsum[ni] += pv;
          pk[ni][mt * 4 + r] = (bf16_t)pv;
        }

    // O += P*V: V B-frag b128 direct from global, sigma-permuted keys
#pragma unroll
    for (int nd = 0; nd < 4; ++nd) {
      bf16x8 vfr = *(const bf16x8*)&vg[((wk * 4 + nd) * 64 + lane) * 8];
#pragma unroll
      for (int ni = 0; ni < 2; ++ni)
        oacc[ni][nd] = MFMA32(pk[ni], vfr, oacc[ni][nd]);
    }
  }

  // lsum: quad-reduce -> every lane holds this wave's total for q = ni*16+l15
#pragma unroll
  for (int ni = 0; ni < 2; ++ni) {
    lsum[ni] += __shfl_xor(lsum[ni], 16);
    lsum[ni] += __shfl_xor(lsum[ni], 32);
  }
  if (quad == 0) {
#pragma unroll
    for (int ni = 0; ni < 2; ++ni) Ls[wk][wq][ni][l15] = lsum[ni];
  }

  // Round 1: partner wk^1 (same wq).  Keep d-half h=wk&1, send the other half.
  const int h = wk & 1;
#pragma unroll
  for (int ni = 0; ni < 2; ++ni)
#pragma unroll
    for (int ndl = 0; ndl < 2; ++ndl)
      *(floatx4*)&Ox[w ^ 2][ni][ndl][lane][0] = oacc[ni][2 * (1 - h) + ndl];
  __syncthreads();
#pragma unroll
  for (int ni = 0; ni < 2; ++ni)
#pragma unroll
    for (int ndl = 0; ndl < 2; ++ndl)
      oacc[ni][2 * h + ndl] += *(floatx4*)&Ox[w][ni][ndl][lane][0];

  // row-sum totals (all 4 key-quarters)
  float tot[2][4];
#pragma unroll
  for (int ni = 0; ni < 2; ++ni)
#pragma unroll
    for (int r = 0; r < 4; ++r)
      tot[ni][r] = Ls[0][wq][ni][quad * 4 + r] + Ls[1][wq][ni][quad * 4 + r] +
                   Ls[2][wq][ni][quad * 4 + r] + Ls[3][wq][ni][quad * 4 + r];
  __syncthreads();

  // Round 2: partner wk^2 (same wq, same d-half).  Own nd = 2h + (wk>>1).
  const int sub = wk >> 1;
  const int nd_own = 2 * h + sub;
#pragma unroll
  for (int ni = 0; ni < 2; ++ni)
    *(floatx4*)&Ox[w ^ 4][ni][0][lane][0] = oacc[ni][2 * h + (1 - sub)];
  __syncthreads();

  const int bb = bh / 12, hh = bh % 12;
#pragma unroll
  for (int ni = 0; ni < 2; ++ni) {
    floatx4 o = oacc[ni][nd_own];
    o += *(floatx4*)&Ox[w][ni][0][lane][0];
    const int col = hh * 64 + nd_own * 16 + l15;
#pragma unroll
    for (int r = 0; r < 4; ++r) {
      const int tok = q0 + wq * 32 + ni * 16 + quad * 4 + r;
      Y[(bb * 2048 + tok) * 768 + col] = (bf16_t)(o[r] / tot[ni][r]);
    }
  }
}

// ------------------------------------------------------------------ launch --
extern "C" void kernel_launch(void* const* d_in, const int* in_sizes, int n_in,
                              void* d_out, int out_size, void* d_ws, size_t ws_size,
                              hipStream_t stream) {
  const float* x  = (const float*)d_in[0];
  const float* Wq = (const float*)d_in[1];
  const float* bq = (const float*)d_in[2];
  const float* Wk = (const float*)d_in[3];
  const float* bk = (const float*)d_in[4];
  const float* Wv = (const float*)d_in[5];
  const float* bv = (const float*)d_in[6];
  const float* Wp = (const float*)d_in[7];
  const float* bp = (const float*)d_in[8];
  float* out = (float*)d_out;

  char* ws = (char*)d_ws;
  bf16_t* xb  = (bf16_t*)ws; ws += (size_t)4096 * 768 * 2;
  bf16_t* WqT = (bf16_t*)ws; ws += (size_t)768 * 768 * 2;
  bf16_t* WkT = (bf16_t*)ws; ws += (size_t)768 * 768 * 2;
  bf16_t* WvT = (bf16_t*)ws; ws += (size_t)768 * 768 * 2;
  bf16_t* WpT = (bf16_t*)ws; ws += (size_t)768 * 768 * 2;
  bf16_t* qw  = (bf16_t*)ws; ws += (size_t)24 * 2048 * 64 * 2;
  bf16_t* kw  = (bf16_t*)ws; ws += (size_t)24 * 2048 * 64 * 2;
  bf16_t* vtw = (bf16_t*)ws; ws += (size_t)24 * 2048 * 64 * 2;
  bf16_t* yw  = (bf16_t*)ws; ws += (size_t)4096 * 768 * 2;

  cvt_x_kernel<<<3072, 256, 0, stream>>>(x, xb);
  cvt_wt_kernel<<<dim3(12, 12, 4), 256, 0, stream>>>(Wq, Wk, Wv, Wp, WqT, WkT, WvT, WpT);

  gemm_qkv<<<dim3(32, 6, 3), 256, 0, stream>>>(xb, WqT, WkT, WvT, bq, bk, bv, qw, kw, vtw);
  attn_kernel<<<dim3(32, 24), 512, 0, stream>>>(qw, kw, vtw, yw);
  gemm_proj<<<dim3(32, 6), 256, 0, stream>>>(yw, WpT, bp, out);
}

// Round 9
// 193.688 us; speedup vs baseline: 1.9518x; 1.9518x over previous
//
#include <hip/hip_runtime.h>

// MultiHeadAttention: B=2, N=2048, C=768, H=12, DH=64. fp32 in/out, bf16 MFMA compute.
// R9 = R8 with the runtime-register-index bug fixed: R8's O-reduction indexed
// oacc[][] with runtime (wave-uniform) indices -> compiler demoted oacc to
// scratch for the WHOLE kernel (VGPR=36, 766 MB scratch writes).  Reduction now
// uses compile-time nd loops + wave-uniform predication; register indices are
// constants, only LDS addresses are runtime.

typedef __bf16 bf16_t;
typedef __bf16 bf16x8 __attribute__((ext_vector_type(8)));
typedef __bf16 bf16x4 __attribute__((ext_vector_type(4)));
typedef float  floatx4 __attribute__((ext_vector_type(4)));
typedef unsigned int u32;

#define MFMA32(a, b, c) __builtin_amdgcn_mfma_f32_16x16x32_bf16(a, b, c, 0, 0, 0)

__device__ __forceinline__ void async16(const bf16_t* g, bf16_t* l) {
  __builtin_amdgcn_global_load_lds(
      (const __attribute__((address_space(1))) u32*)g,
      (__attribute__((address_space(3))) u32*)l, 16, 0, 0);
}

// ---------------------------------------------------------------- converts --
__global__ __launch_bounds__(256) void cvt_x_kernel(const float* __restrict__ x,
                                                    bf16_t* __restrict__ xb) {
  int i = blockIdx.x * 256 + threadIdx.x;
  floatx4 v = ((const floatx4*)x)[i];
  bf16x4 o;
  o[0] = (bf16_t)v[0]; o[1] = (bf16_t)v[1]; o[2] = (bf16_t)v[2]; o[3] = (bf16_t)v[3];
  ((bf16x4*)xb)[i] = o;
}

// W [in=768][out=768] fp32 -> WT [out][in] bf16; blockIdx.z picks which matrix.
__global__ __launch_bounds__(256) void cvt_wt_kernel(
    const float* __restrict__ W0, const float* __restrict__ W1,
    const float* __restrict__ W2, const float* __restrict__ W3,
    bf16_t* __restrict__ T0, bf16_t* __restrict__ T1,
    bf16_t* __restrict__ T2, bf16_t* __restrict__ T3) {
  const int z = blockIdx.z;
  const float* W = (z == 0) ? W0 : (z == 1) ? W1 : (z == 2) ? W2 : W3;
  bf16_t* WT = (z == 0) ? T0 : (z == 1) ? T1 : (z == 2) ? T2 : T3;
  __shared__ bf16_t T[64][65];
  const int c = threadIdx.x & 63, r0 = threadIdx.x >> 6;
#pragma unroll
  for (int p = 0; p < 16; ++p) {
    int r = p * 4 + r0;
    T[r][c] = (bf16_t)W[(blockIdx.y * 64 + r) * 768 + blockIdx.x * 64 + c];
  }
  __syncthreads();
#pragma unroll
  for (int p = 0; p < 16; ++p) {
    int r = p * 4 + r0;
    WT[(blockIdx.x * 64 + r) * 768 + blockIdx.y * 64 + c] = T[c][r];
  }
}

// ------------------------------------------------------------------- GEMMs --
// 128x128 tile, BK=64, pitch 64 elems (128 B), XOR swizzle: oct j of row r is
// stored at slot j^(r&7).  Staging permutes the SOURCE column (LDS dst must be
// lane-linear for global_load_lds); consumers XOR their oct index.

// Fragment-order layouts (per bh, per 128-key tile kt):
//  K: elem(key,d) -> kt*8192 + ((nk*2+kk)*64 + quad*16 + l15)*8 + j
//  V (sigma-permuted for x32 PV): elem(key,d) ->
//     kt*8192 + ((g*4+nd)*64 + qv*16 + dl15)*8 + jv
//     g=key128>>5, o=key128&31, qv=(o&15)>>2, jv=(o&3)+((o&16)>>2),
//     nd=d>>4, dl15=d&15

// Fused QKV, M = output channels (768), N = tokens (4096).
__global__ __launch_bounds__(256) void gemm_qkv(
    const bf16_t* __restrict__ Xb, const bf16_t* __restrict__ WqT,
    const bf16_t* __restrict__ WkT, const bf16_t* __restrict__ WvT,
    const float* __restrict__ bq, const float* __restrict__ bk,
    const float* __restrict__ bv, bf16_t* __restrict__ qw,
    bf16_t* __restrict__ kw, bf16_t* __restrict__ vtw) {
  __shared__ bf16_t Al[128 * 64];
  __shared__ bf16_t Bl[128 * 64];
  const int z = blockIdx.z;
  const bf16_t* Wt = (z == 0) ? WqT : (z == 1) ? WkT : WvT;
  const float* bias = (z == 0) ? bq : (z == 1) ? bk : bv;
  const float oscale = (z == 0) ? 0.18033688011112042f : 1.0f;  // 0.125*log2(e)

  const int tid = threadIdx.x, lane = tid & 63, w = tid >> 6;
  const int wr = w >> 1, wc = w & 1;
  const int l15 = lane & 15, quad = lane >> 4;
  const int xr = l15 & 7;
  const int m0 = blockIdx.y * 128, n0 = blockIdx.x * 128;

  floatx4 acc[4][4] = {};

  for (int kt = 0; kt < 768; kt += 64) {
#pragma unroll
    for (int p = 0; p < 4; ++p) {               // 16 chunks of 512 elems total
      const int cb = (p * 4 + w) * 64;          // wave-uniform chunk base
      const int c = cb + lane;
      const int r = c >> 3, j = (c & 7) ^ (r & 7);   // source col permuted
      async16(&Wt[(m0 + r) * 768 + kt + j * 8], &Al[cb * 8]);
      async16(&Xb[(n0 + r) * 768 + kt + j * 8], &Bl[cb * 8]);
    }
    __syncthreads();
#pragma unroll
    for (int kk = 0; kk < 2; ++kk) {
      bf16x8 af[4], bfr[4];
#pragma unroll
      for (int i = 0; i < 4; ++i) {
        const int sl = ((kk * 4 + quad) ^ xr) * 8;   // swizzled oct slot
        af[i]  = *(bf16x8*)&Al[(wr * 64 + i * 16 + l15) * 64 + sl];
        bfr[i] = *(bf16x8*)&Bl[(wc * 64 + i * 16 + l15) * 64 + sl];
      }
#pragma unroll
      for (int mi = 0; mi < 4; ++mi)
#pragma unroll
        for (int ni = 0; ni < 4; ++ni)
          acc[mi][ni] = MFMA32(af[mi], bfr[ni], acc[mi][ni]);
    }
    __syncthreads();
  }

  const int hh = (m0 + wr * 64) >> 6;  // head (64-aligned per wave-row)
#pragma unroll
  for (int mi = 0; mi < 4; ++mi) {
    const int d0 = mi * 16 + quad * 4;           // d within head, multiple of 4
    const int gm0 = m0 + wr * 64 + d0;
    float bv4[4];
#pragma unroll
    for (int r = 0; r < 4; ++r) bv4[r] = bias[gm0 + r];
#pragma unroll
    for (int ni = 0; ni < 4; ++ni) {
      const int gn = n0 + wc * 64 + ni * 16 + l15;
      const int bb = gn >> 11, tok = gn & 2047;
      const int bh = bb * 12 + hh;
      if (z == 0) {
        bf16x4 pk;
#pragma unroll
        for (int r = 0; r < 4; ++r)
          pk[r] = (bf16_t)((acc[mi][ni][r] + bv4[r]) * oscale);
        *(bf16x4*)&qw[bh * 131072 + tok * 64 + d0] = pk;
      } else if (z == 1) {
        const int kt2 = tok >> 7, k128 = tok & 127;
        const int nk = k128 >> 4, kl15 = k128 & 15;
        const int kk = d0 >> 5, kq = (d0 >> 3) & 3, j0 = d0 & 7;
        bf16x4 pk;
#pragma unroll
        for (int r = 0; r < 4; ++r)
          pk[r] = (bf16_t)(acc[mi][ni][r] + bv4[r]);
        *(bf16x4*)&kw[bh * 131072 + kt2 * 8192 +
                      ((nk * 2 + kk) * 64 + kq * 16 + kl15) * 8 + j0] = pk;
      } else {
        const int kt2 = tok >> 7, k128 = tok & 127;
        const int g = k128 >> 5, o = k128 & 31;
        const int qv = (o & 15) >> 2, jv = (o & 3) + ((o & 16) >> 2);
        // d = d0 + r -> nd = mi, dl15 = quad*4 + r
        const int base = bh * 131072 + kt2 * 8192 +
                         ((g * 4 + mi) * 64 + qv * 16 + quad * 4) * 8 + jv;
#pragma unroll
        for (int r = 0; r < 4; ++r)
          vtw[base + r * 8] = (bf16_t)(acc[mi][ni][r] + bv4[r]);
      }
    }
  }
}

// Output projection, M = channels: out fp32 [4096 tok][768 ch] via float4 stores.
__global__ __launch_bounds__(256) void gemm_proj(
    const bf16_t* __restrict__ Yb, const bf16_t* __restrict__ WpT,
    const float* __restrict__ bias, float* __restrict__ out) {
  __shared__ bf16_t Al[128 * 64];
  __shared__ bf16_t Bl[128 * 64];
  const int tid = threadIdx.x, lane = tid & 63, w = tid >> 6;
  const int wr = w >> 1, wc = w & 1;
  const int l15 = lane & 15, quad = lane >> 4;
  const int xr = l15 & 7;
  const int m0 = blockIdx.y * 128, n0 = blockIdx.x * 128;

  floatx4 acc[4][4] = {};

  for (int kt = 0; kt < 768; kt += 64) {
#pragma unroll
    for (int p = 0; p < 4; ++p) {
      const int cb = (p * 4 + w) * 64;
      const int c = cb + lane;
      const int r = c >> 3, j = (c & 7) ^ (r & 7);
      async16(&WpT[(m0 + r) * 768 + kt + j * 8], &Al[cb * 8]);
      async16(&Yb[(n0 + r) * 768 + kt + j * 8], &Bl[cb * 8]);
    }
    __syncthreads();
#pragma unroll
    for (int kk = 0; kk < 2; ++kk) {
      bf16x8 af[4], bfr[4];
#pragma unroll
      for (int i = 0; i < 4; ++i) {
        const int sl = ((kk * 4 + quad) ^ xr) * 8;
        af[i]  = *(bf16x8*)&Al[(wr * 64 + i * 16 + l15) * 64 + sl];
        bfr[i] = *(bf16x8*)&Bl[(wc * 64 + i * 16 + l15) * 64 + sl];
      }
#pragma unroll
      for (int mi = 0; mi < 4; ++mi)
#pragma unroll
        for (int ni = 0; ni < 4; ++ni)
          acc[mi][ni] = MFMA32(af[mi], bfr[ni], acc[mi][ni]);
    }
    __syncthreads();
  }

#pragma unroll
  for (int mi = 0; mi < 4; ++mi) {
    const int gm0 = m0 + wr * 64 + mi * 16 + quad * 4;
    floatx4 bv4;
#pragma unroll
    for (int r = 0; r < 4; ++r) bv4[r] = bias[gm0 + r];
#pragma unroll
    for (int ni = 0; ni < 4; ++ni) {
      const int gn = n0 + wc * 64 + ni * 16 + l15;
      floatx4 v = acc[mi][ni] + bv4;
      *(floatx4*)&out[gn * 768 + gm0] = v;
    }
  }
}

// --------------------------------------------------------------- attention --
// Block: one (b,h), 64 Q rows, 512 threads = 8 waves.  Wave w: wq=w&1 = 32-q
// half, wk=w>>1 = 32-key quarter.  K/V fragments read directly from global
// (lane-contiguous b128, L2-resident); no LDS staging, no barriers in K-loop.
// End: 2-round tree reduction; ALL register-array indices compile-time.
__global__ __launch_bounds__(512, 4) void attn_kernel(
    const bf16_t* __restrict__ Q, const bf16_t* __restrict__ Kf,
    const bf16_t* __restrict__ Vf, bf16_t* __restrict__ Y) {
  __shared__ __align__(16) float Ox[8][2][2][64][4];  // 32 KB exchange
  __shared__ float Ls[4][2][2][16];                   // [wk][wq][ni][l15]

  const int tid = threadIdx.x, lane = tid & 63, w = tid >> 6;
  const int wq = w & 1, wk = w >> 1;
  const int l15 = lane & 15, quad = lane >> 4;
  const int bh = blockIdx.y;
  const int q0 = blockIdx.x * 64;
  const bf16_t* Qb = Q + bh * 131072;
  const bf16_t* Kb = Kf + bh * 131072;
  const bf16_t* Vb = Vf + bh * 131072;

  bf16x8 qf[2][2];  // B-frag: n=q over l15, k=dh over quad*8+j
#pragma unroll
  for (int ni = 0; ni < 2; ++ni)
#pragma unroll
    for (int kk = 0; kk < 2; ++kk)
      qf[ni][kk] = *(const bf16x8*)&Qb[(q0 + wq * 32 + ni * 16 + l15) * 64 +
                                       kk * 32 + quad * 8];

  floatx4 oacc[2][4] = {};   // [ni(q16)][nd(d16)], partial over this wave's keys
  float lsum[2] = {0.f, 0.f};

  for (int kt = 0; kt < 16; ++kt) {
    const bf16_t* kg = Kb + kt * 8192;
    const bf16_t* vg = Vb + kt * 8192;

    bf16x8 kfr[2][2];
#pragma unroll
    for (int mt = 0; mt < 2; ++mt)
#pragma unroll
      for (int kk = 0; kk < 2; ++kk)
        kfr[mt][kk] = *(const bf16x8*)&kg[((wk * 2 + mt) * 2 + kk) * 512 + lane * 8];

    floatx4 s[2][2] = {};  // [mt][ni]
#pragma unroll
    for (int mt = 0; mt < 2; ++mt)
#pragma unroll
      for (int kk = 0; kk < 2; ++kk)
#pragma unroll
        for (int ni = 0; ni < 2; ++ni)
          s[mt][ni] = MFMA32(kfr[mt][kk], qf[ni][kk], s[mt][ni]);

    bf16x8 pk[2];
#pragma unroll
    for (int mt = 0; mt < 2; ++mt)
#pragma unroll
      for (int ni = 0; ni < 2; ++ni)
#pragma unroll
        for (int r = 0; r < 4; ++r) {
          const float pv = __builtin_amdgcn_exp2f(s[mt][ni][r]);
          lsum[ni] += pv;
          pk[ni][mt * 4 + r] = (bf16_t)pv;
        }

#pragma unroll
    for (int nd = 0; nd < 4; ++nd) {
      bf16x8 vfr = *(const bf16x8*)&vg[((wk * 4 + nd) * 64 + lane) * 8];
#pragma unroll
      for (int ni = 0; ni < 2; ++ni)
        oacc[ni][nd] = MFMA32(pk[ni], vfr, oacc[ni][nd]);
    }
  }

  // lsum: quad-reduce -> every lane holds this wave's total for q = ni*16+l15
#pragma unroll
  for (int ni = 0; ni < 2; ++ni) {
    lsum[ni] += __shfl_xor(lsum[ni], 16);
    lsum[ni] += __shfl_xor(lsum[ni], 32);
  }
  if (quad == 0) {
#pragma unroll
    for (int ni = 0; ni < 2; ++ni) Ls[wk][wq][ni][l15] = lsum[ni];
  }

  const int h = wk & 1;     // wave-uniform: owned d-half
  const int sub = wk >> 1;  // wave-uniform: owned 16-col within half

  // Round 1: send non-owned d-half to partner w^2.  nd compile-time;
  // conditions wave-uniform -> register indices stay constants.
#pragma unroll
  for (int ni = 0; ni < 2; ++ni)
#pragma unroll
    for (int nd = 0; nd < 4; ++nd)
      if ((nd >> 1) != h)
        *(floatx4*)&Ox[w ^ 2][ni][nd & 1][lane][0] = oacc[ni][nd];
  __syncthreads();
#pragma unroll
  for (int ni = 0; ni < 2; ++ni)
#pragma unroll
    for (int nd = 0; nd < 4; ++nd)
      if ((nd >> 1) == h)
        oacc[ni][nd] += *(floatx4*)&Ox[w][ni][nd & 1][lane][0];

  // row-sum totals (all 4 key-quarters)
  float tot[2][4];
#pragma unroll
  for (int ni = 0; ni < 2; ++ni)
#pragma unroll
    for (int r = 0; r < 4; ++r)
      tot[ni][r] = Ls[0][wq][ni][quad * 4 + r] + Ls[1][wq][ni][quad * 4 + r] +
                   Ls[2][wq][ni][quad * 4 + r] + Ls[3][wq][ni][quad * 4 + r];
  __syncthreads();

  // Round 2: send the non-owned 16-col of the owned half to partner w^4.
#pragma unroll
  for (int ni = 0; ni < 2; ++ni)
#pragma unroll
    for (int nd = 0; nd < 4; ++nd)
      if ((nd >> 1) == h && (nd & 1) != sub)
        *(floatx4*)&Ox[w ^ 4][ni][0][lane][0] = oacc[ni][nd];
  __syncthreads();

  const int bb = bh / 12, hh = bh % 12;
  const int nd_own = 2 * h + sub;  // address use only (not a register index)
#pragma unroll
  for (int ni = 0; ni < 2; ++ni) {
    floatx4 o = {};
#pragma unroll
    for (int nd = 0; nd < 4; ++nd)
      if ((nd >> 1) == h && (nd & 1) == sub) o = oacc[ni][nd];
    o += *(floatx4*)&Ox[w][ni][0][lane][0];
    const int col = hh * 64 + nd_own * 16 + l15;
#pragma unroll
    for (int r = 0; r < 4; ++r) {
      const int tok = q0 + wq * 32 + ni * 16 + quad * 4 + r;
      Y[(bb * 2048 + tok) * 768 + col] = (bf16_t)(o[r] / tot[ni][r]);
    }
  }
}

// ------------------------------------------------------------------ launch --
extern "C" void kernel_launch(void* const* d_in, const int* in_sizes, int n_in,
                              void* d_out, int out_size, void* d_ws, size_t ws_size,
                              hipStream_t stream) {
  const float* x  = (const float*)d_in[0];
  const float* Wq = (const float*)d_in[1];
  const float* bq = (const float*)d_in[2];
  const float* Wk = (const float*)d_in[3];
  const float* bk = (const float*)d_in[4];
  const float* Wv = (const float*)d_in[5];
  const float* bv = (const float*)d_in[6];
  const float* Wp = (const float*)d_in[7];
  const float* bp = (const float*)d_in[8];
  float* out = (float*)d_out;

  char* ws = (char*)d_ws;
  bf16_t* xb  = (bf16_t*)ws; ws += (size_t)4096 * 768 * 2;
  bf16_t* WqT = (bf16_t*)ws; ws += (size_t)768 * 768 * 2;
  bf16_t* WkT = (bf16_t*)ws; ws += (size_t)768 * 768 * 2;
  bf16_t* WvT = (bf16_t*)ws; ws += (size_t)768 * 768 * 2;
  bf16_t* WpT = (bf16_t*)ws; ws += (size_t)768 * 768 * 2;
  bf16_t* qw  = (bf16_t*)ws; ws += (size_t)24 * 2048 * 64 * 2;
  bf16_t* kw  = (bf16_t*)ws; ws += (size_t)24 * 2048 * 64 * 2;
  bf16_t* vtw = (bf16_t*)ws; ws += (size_t)24 * 2048 * 64 * 2;
  bf16_t* yw  = (bf16_t*)ws; ws += (size_t)4096 * 768 * 2;

  cvt_x_kernel<<<3072, 256, 0, stream>>>(x, xb);
  cvt_wt_kernel<<<dim3(12, 12, 4), 256, 0, stream>>>(Wq, Wk, Wv, Wp, WqT, WkT, WvT, WpT);

  gemm_qkv<<<dim3(32, 6, 3), 256, 0, stream>>>(xb, WqT, WkT, WvT, bq, bk, bv, qw, kw, vtw);
  attn_kernel<<<dim3(32, 24), 512, 0, stream>>>(qw, kw, vtw, yw);
  gemm_proj<<<dim3(32, 6), 256, 0, stream>>>(yw, WpT, bp, out);
}

// Round 10
// 193.172 us; speedup vs baseline: 1.9570x; 1.0027x over previous
//
#include <hip/hip_runtime.h>

// MultiHeadAttention: B=2, N=2048, C=768, H=12, DH=64. fp32 in/out, bf16 MFMA compute.
// R10: attn K-loop software-pipelined (manual 2x unroll, double-buffered K frag
// regs; V + next-K loads issued before compute so global latency hides under
// QK+exp2).  cvt_x and cvt_wt merged into one dispatch.  Everything else = R9.

typedef __bf16 bf16_t;
typedef __bf16 bf16x8 __attribute__((ext_vector_type(8)));
typedef __bf16 bf16x4 __attribute__((ext_vector_type(4)));
typedef float  floatx4 __attribute__((ext_vector_type(4)));
typedef unsigned int u32;

#define MFMA32(a, b, c) __builtin_amdgcn_mfma_f32_16x16x32_bf16(a, b, c, 0, 0, 0)

__device__ __forceinline__ void async16(const bf16_t* g, bf16_t* l) {
  __builtin_amdgcn_global_load_lds(
      (const __attribute__((address_space(1))) u32*)g,
      (__attribute__((address_space(3))) u32*)l, 16, 0, 0);
}

// ---------------------------------------------------------------- converts --
// One dispatch: blocks [0,3072) convert x (fp32->bf16, float4/lane);
// blocks [3072,3648) transpose-convert the 4 weight matrices (64x64 tiles).
__global__ __launch_bounds__(256) void cvt_all(
    const float* __restrict__ x, bf16_t* __restrict__ xb,
    const float* __restrict__ W0, const float* __restrict__ W1,
    const float* __restrict__ W2, const float* __restrict__ W3,
    bf16_t* __restrict__ T0, bf16_t* __restrict__ T1,
    bf16_t* __restrict__ T2, bf16_t* __restrict__ T3) {
  if (blockIdx.x < 3072) {
    int i = blockIdx.x * 256 + threadIdx.x;
    floatx4 v = ((const floatx4*)x)[i];
    bf16x4 o;
    o[0] = (bf16_t)v[0]; o[1] = (bf16_t)v[1]; o[2] = (bf16_t)v[2]; o[3] = (bf16_t)v[3];
    ((bf16x4*)xb)[i] = o;
    return;
  }
  const int b = blockIdx.x - 3072;       // 576 blocks: z(4) x 12 x 12
  const int z = b / 144, rem = b % 144;
  const int by = rem / 12, bx = rem % 12;
  const float* W = (z == 0) ? W0 : (z == 1) ? W1 : (z == 2) ? W2 : W3;
  bf16_t* WT = (z == 0) ? T0 : (z == 1) ? T1 : (z == 2) ? T2 : T3;
  __shared__ bf16_t T[64][65];
  const int c = threadIdx.x & 63, r0 = threadIdx.x >> 6;
#pragma unroll
  for (int p = 0; p < 16; ++p) {
    int r = p * 4 + r0;
    T[r][c] = (bf16_t)W[(by * 64 + r) * 768 + bx * 64 + c];
  }
  __syncthreads();
#pragma unroll
  for (int p = 0; p < 16; ++p) {
    int r = p * 4 + r0;
    WT[(bx * 64 + r) * 768 + by * 64 + c] = T[c][r];
  }
}

// ------------------------------------------------------------------- GEMMs --
// 128x128 tile, BK=64, pitch 64 elems, XOR swizzle (source-permuted async
// staging + XOR'd consumer oct) -> conflict-free ds_read_b128, no pad.

// Fragment-order layouts (per bh, per 128-key tile kt):
//  K: elem(key,d) -> kt*8192 + ((nk*2+kk)*64 + quad*16 + l15)*8 + j
//  V (sigma-permuted for x32 PV): elem(key,d) ->
//     kt*8192 + ((g*4+nd)*64 + qv*16 + dl15)*8 + jv
//     g=key128>>5, o=key128&31, qv=(o&15)>>2, jv=(o&3)+((o&16)>>2),
//     nd=d>>4, dl15=d&15

// Fused QKV, M = output channels (768), N = tokens (4096).
__global__ __launch_bounds__(256) void gemm_qkv(
    const bf16_t* __restrict__ Xb, const bf16_t* __restrict__ WqT,
    const bf16_t* __restrict__ WkT, const bf16_t* __restrict__ WvT,
    const float* __restrict__ bq, const float* __restrict__ bk,
    const float* __restrict__ bv, bf16_t* __restrict__ qw,
    bf16_t* __restrict__ kw, bf16_t* __restrict__ vtw) {
  __shared__ bf16_t Al[128 * 64];
  __shared__ bf16_t Bl[128 * 64];
  const int z = blockIdx.z;
  const bf16_t* Wt = (z == 0) ? WqT : (z == 1) ? WkT : WvT;
  const float* bias = (z == 0) ? bq : (z == 1) ? bk : bv;
  const float oscale = (z == 0) ? 0.18033688011112042f : 1.0f;  // 0.125*log2(e)

  const int tid = threadIdx.x, lane = tid & 63, w = tid >> 6;
  const int wr = w >> 1, wc = w & 1;
  const int l15 = lane & 15, quad = lane >> 4;
  const int xr = l15 & 7;
  const int m0 = blockIdx.y * 128, n0 = blockIdx.x * 128;

  floatx4 acc[4][4] = {};

  for (int kt = 0; kt < 768; kt += 64) {
#pragma unroll
    for (int p = 0; p < 4; ++p) {               // 16 chunks of 512 elems total
      const int cb = (p * 4 + w) * 64;          // wave-uniform chunk base
      const int c = cb + lane;
      const int r = c >> 3, j = (c & 7) ^ (r & 7);   // source col permuted
      async16(&Wt[(m0 + r) * 768 + kt + j * 8], &Al[cb * 8]);
      async16(&Xb[(n0 + r) * 768 + kt + j * 8], &Bl[cb * 8]);
    }
    __syncthreads();
#pragma unroll
    for (int kk = 0; kk < 2; ++kk) {
      bf16x8 af[4], bfr[4];
#pragma unroll
      for (int i = 0; i < 4; ++i) {
        const int sl = ((kk * 4 + quad) ^ xr) * 8;   // swizzled oct slot
        af[i]  = *(bf16x8*)&Al[(wr * 64 + i * 16 + l15) * 64 + sl];
        bfr[i] = *(bf16x8*)&Bl[(wc * 64 + i * 16 + l15) * 64 + sl];
      }
#pragma unroll
      for (int mi = 0; mi < 4; ++mi)
#pragma unroll
        for (int ni = 0; ni < 4; ++ni)
          acc[mi][ni] = MFMA32(af[mi], bfr[ni], acc[mi][ni]);
    }
    __syncthreads();
  }

  const int hh = (m0 + wr * 64) >> 6;  // head (64-aligned per wave-row)
#pragma unroll
  for (int mi = 0; mi < 4; ++mi) {
    const int d0 = mi * 16 + quad * 4;           // d within head, multiple of 4
    const int gm0 = m0 + wr * 64 + d0;
    float bv4[4];
#pragma unroll
    for (int r = 0; r < 4; ++r) bv4[r] = bias[gm0 + r];
#pragma unroll
    for (int ni = 0; ni < 4; ++ni) {
      const int gn = n0 + wc * 64 + ni * 16 + l15;
      const int bb = gn >> 11, tok = gn & 2047;
      const int bh = bb * 12 + hh;
      if (z == 0) {
        bf16x4 pk;
#pragma unroll
        for (int r = 0; r < 4; ++r)
          pk[r] = (bf16_t)((acc[mi][ni][r] + bv4[r]) * oscale);
        *(bf16x4*)&qw[bh * 131072 + tok * 64 + d0] = pk;
      } else if (z == 1) {
        const int kt2 = tok >> 7, k128 = tok & 127;
        const int nk = k128 >> 4, kl15 = k128 & 15;
        const int kk = d0 >> 5, kq = (d0 >> 3) & 3, j0 = d0 & 7;
        bf16x4 pk;
#pragma unroll
        for (int r = 0; r < 4; ++r)
          pk[r] = (bf16_t)(acc[mi][ni][r] + bv4[r]);
        *(bf16x4*)&kw[bh * 131072 + kt2 * 8192 +
                      ((nk * 2 + kk) * 64 + kq * 16 + kl15) * 8 + j0] = pk;
      } else {
        const int kt2 = tok >> 7, k128 = tok & 127;
        const int g = k128 >> 5, o = k128 & 31;
        const int qv = (o & 15) >> 2, jv = (o & 3) + ((o & 16) >> 2);
        const int base = bh * 131072 + kt2 * 8192 +
                         ((g * 4 + mi) * 64 + qv * 16 + quad * 4) * 8 + jv;
#pragma unroll
        for (int r = 0; r < 4; ++r)
          vtw[base + r * 8] = (bf16_t)(acc[mi][ni][r] + bv4[r]);
      }
    }
  }
}

// Output projection, M = channels: out fp32 [4096 tok][768 ch] via float4 stores.
__global__ __launch_bounds__(256) void gemm_proj(
    const bf16_t* __restrict__ Yb, const bf16_t* __restrict__ WpT,
    const float* __restrict__ bias, float* __restrict__ out) {
  __shared__ bf16_t Al[128 * 64];
  __shared__ bf16_t Bl[128 * 64];
  const int tid = threadIdx.x, lane = tid & 63, w = tid >> 6;
  const int wr = w >> 1, wc = w & 1;
  const int l15 = lane & 15, quad = lane >> 4;
  const int xr = l15 & 7;
  const int m0 = blockIdx.y * 128, n0 = blockIdx.x * 128;

  floatx4 acc[4][4] = {};

  for (int kt = 0; kt < 768; kt += 64) {
#pragma unroll
    for (int p = 0; p < 4; ++p) {
      const int cb = (p * 4 + w) * 64;
      const int c = cb + lane;
      const int r = c >> 3, j = (c & 7) ^ (r & 7);
      async16(&WpT[(m0 + r) * 768 + kt + j * 8], &Al[cb * 8]);
      async16(&Yb[(n0 + r) * 768 + kt + j * 8], &Bl[cb * 8]);
    }
    __syncthreads();
#pragma unroll
    for (int kk = 0; kk < 2; ++kk) {
      bf16x8 af[4], bfr[4];
#pragma unroll
      for (int i = 0; i < 4; ++i) {
        const int sl = ((kk * 4 + quad) ^ xr) * 8;
        af[i]  = *(bf16x8*)&Al[(wr * 64 + i * 16 + l15) * 64 + sl];
        bfr[i] = *(bf16x8*)&Bl[(wc * 64 + i * 16 + l15) * 64 + sl];
      }
#pragma unroll
      for (int mi = 0; mi < 4; ++mi)
#pragma unroll
        for (int ni = 0; ni < 4; ++ni)
          acc[mi][ni] = MFMA32(af[mi], bfr[ni], acc[mi][ni]);
    }
    __syncthreads();
  }

#pragma unroll
  for (int mi = 0; mi < 4; ++mi) {
    const int gm0 = m0 + wr * 64 + mi * 16 + quad * 4;
    floatx4 bv4;
#pragma unroll
    for (int r = 0; r < 4; ++r) bv4[r] = bias[gm0 + r];
#pragma unroll
    for (int ni = 0; ni < 4; ++ni) {
      const int gn = n0 + wc * 64 + ni * 16 + l15;
      floatx4 v = acc[mi][ni] + bv4;
      *(floatx4*)&out[gn * 768 + gm0] = v;
    }
  }
}

// --------------------------------------------------------------- attention --
// Block: one (b,h), 64 Q rows, 512 threads = 8 waves; wq=w&1 = 32-q half,
// wk=w>>1 = 32-key quarter.  K/V fragments direct from global, software-
// pipelined: V(kt) + K(kt+1) issued before kt's compute; K double-buffered via
// manual 2x unroll.  No barriers in the K-loop.  End: 2-round tree reduction,
// all register indices compile-time.
__global__ __launch_bounds__(512, 4) void attn_kernel(
    const bf16_t* __restrict__ Q, const bf16_t* __restrict__ Kf,
    const bf16_t* __restrict__ Vf, bf16_t* __restrict__ Y) {
  __shared__ __align__(16) float Ox[8][2][2][64][4];  // 32 KB exchange
  __shared__ float Ls[4][2][2][16];                   // [wk][wq][ni][l15]

  const int tid = threadIdx.x, lane = tid & 63, w = tid >> 6;
  const int wq = w & 1, wk = w >> 1;
  const int l15 = lane & 15, quad = lane >> 4;
  const int bh = blockIdx.y;
  const int q0 = blockIdx.x * 64;
  const bf16_t* Qb = Q + bh * 131072;
  const bf16_t* Kb = Kf + bh * 131072;
  const bf16_t* Vb = Vf + bh * 131072;

  bf16x8 qf[2][2];  // B-frag: n=q over l15, k=dh over quad*8+j
#pragma unroll
  for (int ni = 0; ni < 2; ++ni)
#pragma unroll
    for (int kk = 0; kk < 2; ++kk)
      qf[ni][kk] = *(const bf16x8*)&Qb[(q0 + wq * 32 + ni * 16 + l15) * 64 +
                                       kk * 32 + quad * 8];

  floatx4 oacc[2][4] = {};   // [ni(q16)][nd(d16)]
  float lsum[2] = {0.f, 0.f};

  // K fragment addresses (per wave): base + mt/kk strides
  const int kfo = (wk * 2) * 1024 + lane * 8;   // + mt*1024 + kk*512
  const int vfo = (wk * 4) * 512 + lane * 8;    // + nd*512

  bf16x8 kA[2][2], kB[2][2];
#pragma unroll
  for (int mt = 0; mt < 2; ++mt)
#pragma unroll
    for (int kk = 0; kk < 2; ++kk)
      kA[mt][kk] = *(const bf16x8*)&Kb[kfo + mt * 1024 + kk * 512];

#pragma unroll 1
  for (int kt2 = 0; kt2 < 8; ++kt2) {
#pragma unroll
    for (int half = 0; half < 2; ++half) {
      const int kt = kt2 * 2 + half;
      const bf16_t* vg = Vb + kt * 8192;
      const bf16_t* kgn = Kb + ((kt + 1) & 15) * 8192;  // wraps harmlessly

      // Issue V(kt) loads first, then K(kt+1) into the alternate buffer.
      bf16x8 vfr[4];
#pragma unroll
      for (int nd = 0; nd < 4; ++nd)
        vfr[nd] = *(const bf16x8*)&vg[vfo + nd * 512];
      if (half == 0) {
#pragma unroll
        for (int mt = 0; mt < 2; ++mt)
#pragma unroll
          for (int kk = 0; kk < 2; ++kk)
            kB[mt][kk] = *(const bf16x8*)&kgn[kfo + mt * 1024 + kk * 512];
      } else {
#pragma unroll
        for (int mt = 0; mt < 2; ++mt)
#pragma unroll
          for (int kk = 0; kk < 2; ++kk)
            kA[mt][kk] = *(const bf16x8*)&kgn[kfo + mt * 1024 + kk * 512];
      }

      // Compute with current K buffer (kA on half 0, kB on half 1).
      bf16x8 pk[2];
#pragma unroll
      for (int mt = 0; mt < 2; ++mt) {
        floatx4 s[2] = {};
#pragma unroll
        for (int kk = 0; kk < 2; ++kk) {
          const bf16x8 kfr = (half == 0) ? kA[mt][kk] : kB[mt][kk];
#pragma unroll
          for (int ni = 0; ni < 2; ++ni)
            s[ni] = MFMA32(kfr, qf[ni][kk], s[ni]);
        }
#pragma unroll
        for (int ni = 0; ni < 2; ++ni)
#pragma unroll
          for (int r = 0; r < 4; ++r) {
            const float pv = __builtin_amdgcn_exp2f(s[ni][r]);
            lsum[ni] += pv;
            pk[ni][mt * 4 + r] = (bf16_t)pv;
          }
      }

#pragma unroll
      for (int nd = 0; nd < 4; ++nd)
#pragma unroll
        for (int ni = 0; ni < 2; ++ni)
          oacc[ni][nd] = MFMA32(pk[ni], vfr[nd], oacc[ni][nd]);
    }
  }

  // lsum: quad-reduce -> every lane holds this wave's total for q = ni*16+l15
#pragma unroll
  for (int ni = 0; ni < 2; ++ni) {
    lsum[ni] += __shfl_xor(lsum[ni], 16);
    lsum[ni] += __shfl_xor(lsum[ni], 32);
  }
  if (quad == 0) {
#pragma unroll
    for (int ni = 0; ni < 2; ++ni) Ls[wk][wq][ni][l15] = lsum[ni];
  }

  const int h = wk & 1;     // wave-uniform: owned d-half
  const int sub = wk >> 1;  // wave-uniform: owned 16-col within half

  // Round 1: send non-owned d-half to partner w^2 (register indices constant).
#pragma unroll
  for (int ni = 0; ni < 2; ++ni)
#pragma unroll
    for (int nd = 0; nd < 4; ++nd)
      if ((nd >> 1) != h)
        *(floatx4*)&Ox[w ^ 2][ni][nd & 1][lane][0] = oacc[ni][nd];
  __syncthreads();
#pragma unroll
  for (int ni = 0; ni < 2; ++ni)
#pragma unroll
    for (int nd = 0; nd < 4; ++nd)
      if ((nd >> 1) == h)
        oacc[ni][nd] += *(floatx4*)&Ox[w][ni][nd & 1][lane][0];

  float tot[2][4];
#pragma unroll
  for (int ni = 0; ni < 2; ++ni)
#pragma unroll
    for (int r = 0; r < 4; ++r)
      tot[ni][r] = Ls[0][wq][ni][quad * 4 + r] + Ls[1][wq][ni][quad * 4 + r] +
                   Ls[2][wq][ni][quad * 4 + r] + Ls[3][wq][ni][quad * 4 + r];
  __syncthreads();

  // Round 2: send the non-owned 16-col of the owned half to partner w^4.
#pragma unroll
  for (int ni = 0; ni < 2; ++ni)
#pragma unroll
    for (int nd = 0; nd < 4; ++nd)
      if ((nd >> 1) == h && (nd & 1) != sub)
        *(floatx4*)&Ox[w ^ 4][ni][0][lane][0] = oacc[ni][nd];
  __syncthreads();

  const int bb = bh / 12, hh = bh % 12;
  const int nd_own = 2 * h + sub;  // address use only
#pragma unroll
  for (int ni = 0; ni < 2; ++ni) {
    floatx4 o = {};
#pragma unroll
    for (int nd = 0; nd < 4; ++nd)
      if ((nd >> 1) == h && (nd & 1) == sub) o = oacc[ni][nd];
    o += *(floatx4*)&Ox[w][ni][0][lane][0];
    const int col = hh * 64 + nd_own * 16 + l15;
#pragma unroll
    for (int r = 0; r < 4; ++r) {
      const int tok = q0 + wq * 32 + ni * 16 + quad * 4 + r;
      Y[(bb * 2048 + tok) * 768 + col] = (bf16_t)(o[r] / tot[ni][r]);
    }
  }
}

// ------------------------------------------------------------------ launch --
extern "C" void kernel_launch(void* const* d_in, const int* in_sizes, int n_in,
                              void* d_out, int out_size, void* d_ws, size_t ws_size,
                              hipStream_t stream) {
  const float* x  = (const float*)d_in[0];
  const float* Wq = (const float*)d_in[1];
  const float* bq = (const float*)d_in[2];
  const float* Wk = (const float*)d_in[3];
  const float* bk = (const float*)d_in[4];
  const float* Wv = (const float*)d_in[5];
  const float* bv = (const float*)d_in[6];
  const float* Wp = (const float*)d_in[7];
  const float* bp = (const float*)d_in[8];
  float* out = (float*)d_out;

  char* ws = (char*)d_ws;
  bf16_t* xb  = (bf16_t*)ws; ws += (size_t)4096 * 768 * 2;
  bf16_t* WqT = (bf16_t*)ws; ws += (size_t)768 * 768 * 2;
  bf16_t* WkT = (bf16_t*)ws; ws += (size_t)768 * 768 * 2;
  bf16_t* WvT = (bf16_t*)ws; ws += (size_t)768 * 768 * 2;
  bf16_t* WpT = (bf16_t*)ws; ws += (size_t)768 * 768 * 2;
  bf16_t* qw  = (bf16_t*)ws; ws += (size_t)24 * 2048 * 64 * 2;
  bf16_t* kw  = (bf16_t*)ws; ws += (size_t)24 * 2048 * 64 * 2;
  bf16_t* vtw = (bf16_t*)ws; ws += (size_t)24 * 2048 * 64 * 2;
  bf16_t* yw  = (bf16_t*)ws; ws += (size_t)4096 * 768 * 2;

  cvt_all<<<3648, 256, 0, stream>>>(x, xb, Wq, Wk, Wv, Wp, WqT, WkT, WvT, WpT);
  gemm_qkv<<<dim3(32, 6, 3), 256, 0, stream>>>(xb, WqT, WkT, WvT, bq, bk, bv, qw, kw, vtw);
  attn_kernel<<<dim3(32, 24), 512, 0, stream>>>(qw, kw, vtw, yw);
  gemm_proj<<<dim3(32, 6), 256, 0, stream>>>(yw, WpT, bp, out);
}